// Round 1
// baseline (124.747 us; speedup 1.0000x reference)
//
#include <hip/hip_runtime.h>

#define S_LEN 4096
#define BATCH 2
#define EMB   768
#define NH    12
#define HDIM  64
#define WIN   256

using f32x4  = __attribute__((ext_vector_type(4))) float;
using bf16x8 = __attribute__((ext_vector_type(8))) short;
using u16x8  = __attribute__((ext_vector_type(8))) unsigned short;

__device__ __forceinline__ unsigned short f2bf(float x) {
    unsigned int u = __float_as_uint(x);
    return (unsigned short)((u + 0x7fffu + ((u >> 16) & 1u)) >> 16);
}

// ---------------- fp32 -> bf16 convert, 8 elems/thread ----------------
__global__ void cvt_kernel(const float* __restrict__ in,
                           unsigned short* __restrict__ out, int n8) {
    int i = blockIdx.x * blockDim.x + threadIdx.x;
    if (i >= n8) return;
    const float4* p = reinterpret_cast<const float4*>(in) + (size_t)i * 2;
    float4 a = p[0];
    float4 b = p[1];
    u16x8 o;
    o[0] = f2bf(a.x); o[1] = f2bf(a.y); o[2] = f2bf(a.z); o[3] = f2bf(a.w);
    o[4] = f2bf(b.x); o[5] = f2bf(b.y); o[6] = f2bf(b.z); o[7] = f2bf(b.w);
    reinterpret_cast<u16x8*>(out)[i] = o;
}

// ---------------- fused QKV GEMM ----------------
// C[m,n] = sum_k A[m,k] * W[n,k]  (B^T form), M=8192, K=768, N=3*768
// tile 128x128x32, 4 waves 2x2, each wave 64x64 (4x4 frags of 16x16)
#define GBM 128
#define GBN 128
#define GBK 32

__global__ __launch_bounds__(256) void qkv_gemm(
    const unsigned short* __restrict__ A,
    const unsigned short* __restrict__ Wq,
    const unsigned short* __restrict__ Wk,
    const unsigned short* __restrict__ Wv,
    const float* __restrict__ bq,
    const float* __restrict__ bk,
    const float* __restrict__ bv,
    unsigned short* __restrict__ qo,   // [B][H][S][HD]
    unsigned short* __restrict__ ko,   // [B][H][S][HD]
    unsigned short* __restrict__ vo)   // [B][H][HD][S]  (transposed)
{
    __shared__ unsigned short Asm[GBM * GBK];
    __shared__ unsigned short Bsm[GBN * GBK];
    const int tid  = threadIdx.x;
    const int wave = tid >> 6, lane = tid & 63;
    const int mblk = blockIdx.x;           // 0..63
    const int nblk = blockIdx.y;           // 0..17
    const int wsel = nblk / 6;             // 0=Q 1=K 2=V
    const int nloc0 = (nblk % 6) * GBN;    // 0..640 within the weight
    const unsigned short* Wp = (wsel == 0) ? Wq : ((wsel == 1) ? Wk : Wv);
    const int wm = wave >> 1, wn = wave & 1;

    f32x4 acc[4][4];
#pragma unroll
    for (int i = 0; i < 4; ++i)
#pragma unroll
        for (int j = 0; j < 4; ++j)
            acc[i][j] = (f32x4){0.f, 0.f, 0.f, 0.f};

    const int frow = lane & 15;
    const int fcol = (lane >> 4) * 8;
    const int srow  = lane >> 2;          // 0..15 within a 16-row wave-load
    const int sbyte = (lane & 3) * 16;    // 0..48 byte offset within 64B row

    const char* Abase = (const char*)(A  + (size_t)(mblk * GBM) * EMB);
    const char* Bbase = (const char*)(Wp + (size_t)nloc0 * EMB);

    for (int k0 = 0; k0 < EMB; k0 += GBK) {
#pragma unroll
        for (int rep = 0; rep < 2; ++rep) {
            int r0 = wave * 32 + rep * 16;
            const char* ga = Abase + (size_t)(r0 + srow) * (EMB * 2) + k0 * 2 + sbyte;
            const char* gb = Bbase + (size_t)(r0 + srow) * (EMB * 2) + k0 * 2 + sbyte;
            __builtin_amdgcn_global_load_lds(
                (const __attribute__((address_space(1))) unsigned int*)ga,
                (__attribute__((address_space(3))) unsigned int*)&Asm[r0 * GBK], 16, 0, 0);
            __builtin_amdgcn_global_load_lds(
                (const __attribute__((address_space(1))) unsigned int*)gb,
                (__attribute__((address_space(3))) unsigned int*)&Bsm[r0 * GBK], 16, 0, 0);
        }
        __syncthreads();
        bf16x8 af[4], bfr[4];
#pragma unroll
        for (int mi = 0; mi < 4; ++mi)
            af[mi] = *reinterpret_cast<const bf16x8*>(&Asm[(wm * 64 + mi * 16 + frow) * GBK + fcol]);
#pragma unroll
        for (int ni = 0; ni < 4; ++ni)
            bfr[ni] = *reinterpret_cast<const bf16x8*>(&Bsm[(wn * 64 + ni * 16 + frow) * GBK + fcol]);
#pragma unroll
        for (int mi = 0; mi < 4; ++mi)
#pragma unroll
            for (int ni = 0; ni < 4; ++ni)
                acc[mi][ni] = __builtin_amdgcn_mfma_f32_16x16x32_bf16(af[mi], bfr[ni], acc[mi][ni], 0, 0, 0);
        __syncthreads();
    }

    // epilogue
    const float* bias = (wsel == 0) ? bq : ((wsel == 1) ? bk : bv);
    const int rowg = (lane >> 4) * 4;
#pragma unroll
    for (int mi = 0; mi < 4; ++mi) {
        int mbase = mblk * GBM + wm * 64 + mi * 16 + rowg;
#pragma unroll
        for (int ni = 0; ni < 4; ++ni) {
            int nl = nloc0 + wn * 64 + ni * 16 + frow;   // 0..767
            float bb = bias[nl];
            int h = nl >> 6, hd = nl & 63;
#pragma unroll
            for (int r = 0; r < 4; ++r) {
                int mm = mbase + r;
                int b = mm >> 12, s = mm & 4095;
                float v = acc[mi][ni][r] + bb;
                if (wsel == 0) {
                    v *= 0.125f;
                    qo[((size_t)(b * NH + h) * S_LEN + s) * HDIM + hd] = f2bf(v);
                } else if (wsel == 1) {
                    ko[((size_t)(b * NH + h) * S_LEN + s) * HDIM + hd] = f2bf(v);
                } else {
                    vo[((size_t)(b * NH + h) * HDIM + hd) * S_LEN + s] = f2bf(v);
                }
            }
        }
    }
}

// ---------------- banded flash attention ----------------
// block = (b, h, 64 queries); 4 waves x 16 rows; 9 key chunks of 64
#define QB  64
#define KC  64
#define NCH 9

__global__ __launch_bounds__(256) void banded_attn(
    const unsigned short* __restrict__ qg,   // [B][H][S][HD]
    const unsigned short* __restrict__ kg,   // [B][H][S][HD]
    const unsigned short* __restrict__ vtg,  // [B][H][HD][S]
    float* __restrict__ out)                 // [B][S][E]
{
    __shared__ unsigned short Ksm[KC * HDIM];        // [key][hd] swizzled
    __shared__ unsigned short Vsm[HDIM * KC];        // [hd][key] swizzled
    __shared__ unsigned short Psm[4][16 * KC];       // per-wave [qrow][key] swizzled

    const int tid  = threadIdx.x;
    const int wave = tid >> 6, lane = tid & 63;
    const int qb = blockIdx.x * QB;
    const int h  = blockIdx.y, b = blockIdx.z;

    const unsigned short* qp = qg  + (size_t)(b * NH + h) * S_LEN * HDIM;
    const unsigned short* kp = kg  + (size_t)(b * NH + h) * S_LEN * HDIM;
    const unsigned short* vp = vtg + (size_t)(b * NH + h) * HDIM * S_LEN;

    const int frow = lane & 15;
    const int g    = lane >> 4;
    const int fcol = g * 8;

    // Q fragments, held for the whole block
    bf16x8 qf[2];
    {
        const unsigned short* qr = qp + (size_t)(qb + wave * 16 + frow) * HDIM;
        qf[0] = *reinterpret_cast<const bf16x8*>(qr + fcol);
        qf[1] = *reinterpret_cast<const bf16x8*>(qr + 32 + fcol);
    }

    float m_run[4], l_part[4];
    f32x4 o_acc[4];
#pragma unroll
    for (int r = 0; r < 4; ++r) { m_run[r] = -1e30f; l_part[r] = 0.f; }
#pragma unroll
    for (int ni = 0; ni < 4; ++ni) o_acc[ni] = (f32x4){0.f, 0.f, 0.f, 0.f};

    const int srow = tid >> 2;          // 0..63
    const int ec0  = (tid & 3) * 16;    // element col base (16 elems/thread)
    const int swz_s = (srow & 7) << 3;  // staging swizzle (elements)

    for (int c = 0; c < NCH; ++c) {
        const int ks = qb - WIN + c * KC;
        // ---- stage K chunk [key][hd] ----
        {
            int j  = ks + srow;
            int jc = min(max(j, 0), S_LEN - 1);
            const unsigned short* kr = kp + (size_t)jc * HDIM;
            bf16x8 k0 = *reinterpret_cast<const bf16x8*>(kr + ec0);
            bf16x8 k1 = *reinterpret_cast<const bf16x8*>(kr + ec0 + 8);
            *reinterpret_cast<bf16x8*>(&Ksm[srow * KC + (ec0 ^ swz_s)])       = k0;
            *reinterpret_cast<bf16x8*>(&Ksm[srow * KC + ((ec0 + 8) ^ swz_s)]) = k1;
            // ---- stage V^T chunk [hd][key] ----
            bf16x8 v0, v1;
            if (ks >= 0 && ks + KC <= S_LEN) {
                const unsigned short* vr = vp + (size_t)srow * S_LEN + ks;
                v0 = *reinterpret_cast<const bf16x8*>(vr + ec0);
                v1 = *reinterpret_cast<const bf16x8*>(vr + ec0 + 8);
            } else {
#pragma unroll
                for (int e = 0; e < 8; ++e) {
                    int j0 = min(max(ks + ec0 + e, 0), S_LEN - 1);
                    int j1 = min(max(ks + ec0 + 8 + e, 0), S_LEN - 1);
                    v0[e] = (short)vp[(size_t)srow * S_LEN + j0];
                    v1[e] = (short)vp[(size_t)srow * S_LEN + j1];
                }
            }
            *reinterpret_cast<bf16x8*>(&Vsm[srow * KC + (ec0 ^ swz_s)])       = v0;
            *reinterpret_cast<bf16x8*>(&Vsm[srow * KC + ((ec0 + 8) ^ swz_s)]) = v1;
        }
        __syncthreads();

        // ---- scores S = Q K^T  (16 q x 64 keys per wave) ----
        f32x4 sc[4];
#pragma unroll
        for (int ni = 0; ni < 4; ++ni) sc[ni] = (f32x4){0.f, 0.f, 0.f, 0.f};
#pragma unroll
        for (int ni = 0; ni < 4; ++ni) {
            int krow = ni * 16 + frow;
            int sw   = (krow & 7) << 3;
            bf16x8 kf0 = *reinterpret_cast<const bf16x8*>(&Ksm[krow * KC + (fcol ^ sw)]);
            bf16x8 kf1 = *reinterpret_cast<const bf16x8*>(&Ksm[krow * KC + ((32 + fcol) ^ sw)]);
            sc[ni] = __builtin_amdgcn_mfma_f32_16x16x32_bf16(qf[0], kf0, sc[ni], 0, 0, 0);
            sc[ni] = __builtin_amdgcn_mfma_f32_16x16x32_bf16(qf[1], kf1, sc[ni], 0, 0, 0);
        }

        // ---- mask + online softmax ----
        const int qrow0 = qb + wave * 16 + g * 4;
        float pm[4][4];
        float rm[4];
#pragma unroll
        for (int r = 0; r < 4; ++r) rm[r] = -3e38f;
#pragma unroll
        for (int ni = 0; ni < 4; ++ni) {
            int key = ks + ni * 16 + frow;
#pragma unroll
            for (int r = 0; r < 4; ++r) {
                int qi = qrow0 + r;
                float s = sc[ni][r];
                bool valid = (key >= 0) && (key < S_LEN) &&
                             (key - qi <= WIN) && (qi - key <= WIN);
                s = valid ? s : -3e38f;
                pm[ni][r] = s;
                rm[r] = fmaxf(rm[r], s);
            }
        }
#pragma unroll
        for (int d = 1; d < 16; d <<= 1)
#pragma unroll
            for (int r = 0; r < 4; ++r)
                rm[r] = fmaxf(rm[r], __shfl_xor(rm[r], d, 64));

        float scale[4];
#pragma unroll
        for (int r = 0; r < 4; ++r) {
            float mn = fmaxf(m_run[r], rm[r]);
            scale[r] = __expf(m_run[r] - mn);
            m_run[r] = mn;
        }
#pragma unroll
        for (int ni = 0; ni < 4; ++ni)
#pragma unroll
            for (int r = 0; r < 4; ++r)
                o_acc[ni][r] *= scale[r];

        // P = exp(S - m), write to per-wave LDS (swizzled), track row sums
#pragma unroll
        for (int r = 0; r < 4; ++r) {
            float psum = 0.f;
#pragma unroll
            for (int ni = 0; ni < 4; ++ni) {
                float p = __expf(pm[ni][r] - m_run[r]);
                psum += p;
                int prow  = g * 4 + r;
                int pelem = (ni * 16 + frow) ^ ((prow & 7) << 3);
                Psm[wave][prow * KC + pelem] = f2bf(p);
            }
            l_part[r] = l_part[r] * scale[r] + psum;
        }

        asm volatile("s_waitcnt lgkmcnt(0)" ::: "memory");
        __builtin_amdgcn_sched_barrier(0);

        // ---- PV: O += P V ----
        bf16x8 pf[2];
#pragma unroll
        for (int kk = 0; kk < 2; ++kk) {
            int sw = (frow & 7) << 3;
            pf[kk] = *reinterpret_cast<const bf16x8*>(&Psm[wave][frow * KC + ((kk * 32 + fcol) ^ sw)]);
        }
#pragma unroll
        for (int ni = 0; ni < 4; ++ni) {
            int vrow = ni * 16 + frow;
            int sw   = (vrow & 7) << 3;
#pragma unroll
            for (int kk = 0; kk < 2; ++kk) {
                bf16x8 vf = *reinterpret_cast<const bf16x8*>(&Vsm[vrow * KC + ((kk * 32 + fcol) ^ sw)]);
                o_acc[ni] = __builtin_amdgcn_mfma_f32_16x16x32_bf16(pf[kk], vf, o_acc[ni], 0, 0, 0);
            }
        }
        __syncthreads();
    }

    // ---- finalize: reduce l across the 16-lane group, divide, store fp32 ----
#pragma unroll
    for (int d = 1; d < 16; d <<= 1)
#pragma unroll
        for (int r = 0; r < 4; ++r)
            l_part[r] += __shfl_xor(l_part[r], d, 64);

    const int qrow0 = qb + wave * 16 + g * 4;
#pragma unroll
    for (int r = 0; r < 4; ++r) {
        float inv = 1.0f / l_part[r];
        int s = qrow0 + r;
        size_t obase = ((size_t)b * S_LEN + s) * EMB + h * HDIM;
#pragma unroll
        for (int ni = 0; ni < 4; ++ni)
            out[obase + ni * 16 + frow] = o_acc[ni][r] * inv;
    }
}

// ---------------- launcher ----------------
extern "C" void kernel_launch(void* const* d_in, const int* in_sizes, int n_in,
                              void* d_out, int out_size, void* d_ws, size_t ws_size,
                              hipStream_t stream) {
    const float* hs = (const float*)d_in[0];
    const float* Wq = (const float*)d_in[1];
    const float* Wk = (const float*)d_in[2];
    const float* Wv = (const float*)d_in[3];
    const float* bq = (const float*)d_in[4];
    const float* bk = (const float*)d_in[5];
    const float* bv = (const float*)d_in[6];
    float* out = (float*)d_out;

    char* w = (char*)d_ws;
    unsigned short* hs_bf = (unsigned short*)w;                       // 12,582,912 B
    unsigned short* wq_bf = (unsigned short*)(w + 12582912);          // 1,179,648 B each
    unsigned short* wk_bf = wq_bf + 589824;
    unsigned short* wv_bf = wk_bf + 589824;
    unsigned short* q_ws  = (unsigned short*)(w + 12582912 + 3 * 1179648);
    unsigned short* k_ws  = q_ws + 6291456;
    unsigned short* v_ws  = k_ws + 6291456;

    cvt_kernel<<<3072, 256, 0, stream>>>(hs, hs_bf, 786432);
    cvt_kernel<<<288, 256, 0, stream>>>(Wq, wq_bf, 73728);
    cvt_kernel<<<288, 256, 0, stream>>>(Wk, wk_bf, 73728);
    cvt_kernel<<<288, 256, 0, stream>>>(Wv, wv_bf, 73728);

    qkv_gemm<<<dim3(64, 18), 256, 0, stream>>>(hs_bf, wq_bf, wk_bf, wv_bf,
                                               bq, bk, bv, q_ws, k_ws, v_ws);

    banded_attn<<<dim3(S_LEN / QB, NH, BATCH), 256, 0, stream>>>(q_ws, k_ws, v_ws, out);
}